// Round 13
// baseline (282.420 us; speedup 1.0000x reference)
//
#include <hip/hip_runtime.h>

#define B_ 8
#define S_ 96
#define C_ 256
#define NH_ 8
#define D_ 32
#define M_ (B_*S_*S_)
static const size_t SZ = (size_t)M_ * C_;

typedef unsigned short u16;
typedef short bf16x8 __attribute__((ext_vector_type(8)));
typedef _Float16 hf8 __attribute__((ext_vector_type(8)));
typedef float f32x4 __attribute__((ext_vector_type(4)));

__device__ __forceinline__ u16 f2b(float f) {                // fp32 -> bf16 RNE
    unsigned u = __float_as_uint(f);
    return (u16)((u + 0x7FFFu + ((u >> 16) & 1u)) >> 16);
}
__device__ __forceinline__ float b2f(u16 h) { return __uint_as_float(((unsigned)h) << 16); }
__device__ __forceinline__ u16 f2h(float f) {
    _Float16 h = (_Float16)f;
    return __builtin_bit_cast(u16, h);
}

__device__ __forceinline__ void gload16(const u16* g, u16* l) {
    __builtin_amdgcn_global_load_lds(
        (const __attribute__((address_space(1))) u16*)g,
        (__attribute__((address_space(3))) u16*)l, 16, 0, 0);
}

// ---------------------------------------------------------------------------
// prep_all: union of prep_x (blocks [0,9216)), prep_w ([9216,10240)),
// prep_cw ([10240,10265)). Each path identical to the R12 kernels.
// ---------------------------------------------------------------------------
__global__ __launch_bounds__(256) void prep_all(
    const float* __restrict__ x, u16* __restrict__ xb,
    const float* __restrict__ Wq, const float* __restrict__ Wk,
    const float* __restrict__ Wv, const float* __restrict__ Wo,
    u16* __restrict__ WT,
    const float* __restrict__ cw, u16* __restrict__ cwh)
{
    int bx = blockIdx.x;
    if (bx < 9216) {
        size_t base = ((size_t)bx * 256 + threadIdx.x) * 8;
        float4 a = *(const float4*)(x + base);
        float4 b = *(const float4*)(x + base + 4);
        u16 o[8] = { f2b(a.x), f2b(a.y), f2b(a.z), f2b(a.w),
                     f2b(b.x), f2b(b.y), f2b(b.z), f2b(b.w) };
        *(int4*)(xb + base) = *(int4*)o;
    } else if (bx < 10240) {
        int id = (bx - 9216) * 256 + threadIdx.x;
        int w = id >> 16;
        int r = id & 65535;
        int n = r >> 8;
        int kk = r & 255;
        const float* Wp = (w == 0) ? Wq : (w == 1) ? Wk : (w == 2) ? Wv : Wo;
        WT[(size_t)id] = f2b(Wp[(size_t)kk * 256 + n]);
    } else {
        int id = (bx - 10240) * 256 + threadIdx.x;
        cwh[id] = f2h(cw[id]);
    }
}

// ---------------------------------------------------------------------------
// R4-proven GEMM staging: BK=64, SINGLE buffer, global_load_lds w16,
// XOR-swizzled source slot (slot' = slot ^ (row&7)), linear LDS [128][64].
// ---------------------------------------------------------------------------
#define STAGE4(gbase, lds, k0)                                                  \
    _Pragma("unroll")                                                           \
    for (int i_ = 0; i_ < 4; ++i_) {                                            \
        int row8 = wave * 32 + i_ * 8;                                          \
        gload16((gbase) + (size_t)(row8 + lrow) * C_ + (k0) + sslot * 8,        \
                (lds) + row8 * 64);                                             \
    }
#define FRAG4(lds, rowi, ks) \
    (*(const bf16x8*)((lds) + (rowi) * 64 + (((ks) * 4 + kg) ^ ((rowi) & 7)) * 8))

// ---------------------------------------------------------------------------
// proj_fused: block-level union of R12's proj_q and proj_kv (inner loops
// byte-identical). grid (4, 576): bx<2 -> q path (colbase=(bx&1)*128),
// bx>=2 -> kv path. One 48KB LDS pool. Co-schedules 2304 blocks so q-blocks
// fill kv-blocks' latency gaps. VGPR = max(paths) <= 256 @ bounds(256,2).
// ---------------------------------------------------------------------------
__global__ __launch_bounds__(256, 2) void proj_fused(
    const u16* __restrict__ xb, const float* __restrict__ enc,
    const u16* __restrict__ WT,
    const float* __restrict__ bq, const float* __restrict__ bk,
    const float* __restrict__ bv,
    u16* __restrict__ q, u16* __restrict__ k, u16* __restrict__ v)
{
    __shared__ u16 smem[3 * 8192];       // 48KB
    const int t = threadIdx.x;
    const int bx = blockIdx.x;
    const int colbase = (bx & 1) * 128;
    const int m0 = blockIdx.y * 128;
    const int wave = t >> 6, lane = t & 63;
    const int wr = wave >> 1, wc = wave & 1;
    const int l16 = lane & 15, kg = lane >> 4;
    const int lrow = lane >> 3;
    const int sslot = (lane & 7) ^ lrow;

    const u16* gA = xb + (size_t)m0 * C_;

    if (bx < 2) {
        // ----- proj_q path (R12 verbatim) -----
        u16* sA = smem;
        u16* sB = smem + 8192;
        const u16* gB = WT + (size_t)colbase * C_;

        f32x4 acc[4][4];
#pragma unroll
        for (int i = 0; i < 4; ++i)
#pragma unroll
            for (int j = 0; j < 4; ++j) acc[i][j] = (f32x4){0.f, 0.f, 0.f, 0.f};

        STAGE4(gA, sA, 0); STAGE4(gB, sB, 0);
        for (int k0 = 0; k0 < 256; k0 += 64) {
            __syncthreads();
#pragma unroll
            for (int ks = 0; ks < 2; ++ks) {
                bf16x8 af[4], bf[4];
#pragma unroll
                for (int mi = 0; mi < 4; ++mi)
                    af[mi] = FRAG4(sA, wr * 64 + mi * 16 + l16, ks);
#pragma unroll
                for (int ni = 0; ni < 4; ++ni)
                    bf[ni] = FRAG4(sB, wc * 64 + ni * 16 + l16, ks);
#pragma unroll
                for (int mi = 0; mi < 4; ++mi)
#pragma unroll
                    for (int ni = 0; ni < 4; ++ni)
                        acc[mi][ni] = __builtin_amdgcn_mfma_f32_16x16x32_bf16(
                            af[mi], bf[ni], acc[mi][ni], 0, 0, 0);
            }
            __syncthreads();
            if (k0 < 192) { STAGE4(gA, sA, k0 + 64); STAGE4(gB, sB, k0 + 64); }
        }

#pragma unroll
        for (int mi = 0; mi < 4; ++mi)
#pragma unroll
            for (int ni = 0; ni < 4; ++ni) {
                int col = colbase + wc * 64 + ni * 16 + l16;
                float bqv = bq[col];
#pragma unroll
                for (int r = 0; r < 4; ++r) {
                    int row = m0 + wr * 64 + mi * 16 + kg * 4 + r;
                    q[(size_t)row * 256 + col] = f2b(acc[mi][ni][r] + bqv);
                }
            }
    } else {
        // ----- proj_kv path (R12 verbatim) -----
        u16* sA  = smem;
        u16* sB0 = smem + 8192;
        u16* sB1 = smem + 16384;
        const u16* gB0 = WT + 65536 + (size_t)colbase * C_;
        const u16* gB1 = WT + 2 * 65536 + (size_t)colbase * C_;

        f32x4 acck[4][4], accv[4][4];
#pragma unroll
        for (int i = 0; i < 4; ++i)
#pragma unroll
            for (int j = 0; j < 4; ++j) {
                acck[i][j] = (f32x4){0.f, 0.f, 0.f, 0.f};
                accv[i][j] = (f32x4){0.f, 0.f, 0.f, 0.f};
            }

        STAGE4(gA, sA, 0); STAGE4(gB0, sB0, 0); STAGE4(gB1, sB1, 0);
        for (int k0 = 0; k0 < 256; k0 += 64) {
            __syncthreads();
#pragma unroll
            for (int ks = 0; ks < 2; ++ks) {
                bf16x8 af[4], b0[4], b1[4];
#pragma unroll
                for (int mi = 0; mi < 4; ++mi)
                    af[mi] = FRAG4(sA, wr * 64 + mi * 16 + l16, ks);
#pragma unroll
                for (int ni = 0; ni < 4; ++ni) {
                    b0[ni] = FRAG4(sB0, wc * 64 + ni * 16 + l16, ks);
                    b1[ni] = FRAG4(sB1, wc * 64 + ni * 16 + l16, ks);
                }
#pragma unroll
                for (int mi = 0; mi < 4; ++mi)
#pragma unroll
                    for (int ni = 0; ni < 4; ++ni) {
                        acck[mi][ni] = __builtin_amdgcn_mfma_f32_16x16x32_bf16(
                            af[mi], b0[ni], acck[mi][ni], 0, 0, 0);
                        accv[mi][ni] = __builtin_amdgcn_mfma_f32_16x16x32_bf16(
                            af[mi], b1[ni], accv[mi][ni], 0, 0, 0);
                    }
            }
            __syncthreads();
            if (k0 < 192) { STAGE4(gA, sA, k0 + 64); STAGE4(gB0, sB0, k0 + 64); STAGE4(gB1, sB1, k0 + 64); }
        }

        const float SCALE = 0.17677669529663687f;
#pragma unroll
        for (int mi = 0; mi < 4; ++mi)
#pragma unroll
            for (int ni = 0; ni < 4; ++ni) {
                int col = colbase + wc * 64 + ni * 16 + l16;
                float bkv = bk[col], bvv = bv[col];
#pragma unroll
                for (int r = 0; r < 4; ++r) {
                    int row = m0 + wr * 64 + mi * 16 + kg * 4 + r;
                    size_t off = (size_t)row * 256 + col;
                    float e = enc[off];
                    k[off] = f2b((acck[mi][ni][r] + bkv + e) * SCALE);
                    v[off] = f2h(accv[mi][ni][r] + bvv + e);
                }
            }
    }
}

// ---------------------------------------------------------------------------
// dwconv5x5: v (f16) -> lepe (bf16), packed f16 math, 8 output pixels/thread.
// ---------------------------------------------------------------------------
__global__ __launch_bounds__(256) void dwconv5x5(
    const u16* __restrict__ vh, const u16* __restrict__ cwh,
    const float* __restrict__ cb, u16* __restrict__ lepeb)
{
    size_t tid = (size_t)blockIdx.x * 256 + threadIdx.x;
    int c8 = (int)(tid & 31);
    size_t rest = tid >> 5;
    int wi = (int)(rest % 12);
    size_t tmp = rest / 12;
    int h = (int)(tmp % S_);
    int b = (int)(tmp / S_);
    int w0 = wi * 8;
    int c0 = c8 * 8;

    hf8 z;
#pragma unroll
    for (int q = 0; q < 8; ++q) z[q] = (_Float16)0.f;
    hf8 acc[8] = { z, z, z, z, z, z, z, z };

#pragma unroll
    for (int dy = -2; dy <= 2; ++dy) {
        int hy = h + dy;
        if (hy < 0 || hy >= S_) continue;
        const u16* rowp = vh + (((size_t)b * S_ + hy) * S_) * C_ + c0;
        hf8 vr[12];
#pragma unroll
        for (int i = 0; i < 12; ++i) {
            int c = w0 - 2 + i;
            vr[i] = (c >= 0 && c < S_) ? *(const hf8*)(rowp + (size_t)c * C_) : z;
        }
#pragma unroll
        for (int dx = 0; dx < 5; ++dx) {
            hf8 ww = *(const hf8*)(cwh + (size_t)((dy + 2) * 5 + dx) * C_ + c0);
#pragma unroll
            for (int r = 0; r < 8; ++r) acc[r] += vr[dx + r] * ww;
        }
    }

    float4 cb0 = *(const float4*)(cb + c0);
    float4 cb1 = *(const float4*)(cb + c0 + 4);
    float cbv[8] = { cb0.x, cb0.y, cb0.z, cb0.w, cb1.x, cb1.y, cb1.z, cb1.w };
    size_t pix0 = ((size_t)b * S_ + h) * S_ + w0;
#pragma unroll
    for (int r = 0; r < 8; ++r) {
        u16 o[8];
#pragma unroll
        for (int q = 0; q < 8; ++q) o[q] = f2b((float)acc[r][q] + cbv[q]);
        *(int4*)(lepeb + (pix0 + r) * C_ + c0) = *(int4*)o;
    }
}

// ---------------------------------------------------------------------------
// axial<HM>: MFMA axial attention with LOG-softmax (R10/R12 f16 version).
//  HM=0 (width):  vin = v (f16), vout = v1 (f16, d_out)
//  HM=1 (height): vin = v1 (f16), vout = bf16(out2 + lepe) into qbuf in-place
// ---------------------------------------------------------------------------
template<int HM>
__global__ __launch_bounds__(128, 3) void axial(
    const u16* __restrict__ qb, const u16* __restrict__ kb,
    const u16* __restrict__ vin, void* __restrict__ vout,
    const u16* __restrict__ lep, int ofac, int pstride)
{
    __shared__ u16 sQ[96][56];
    __shared__ u16 sK[96][56];
    __shared__ u16 sVT[32][104];
    __shared__ u16 sAh[2][16][40];

    const int t = threadIdx.x;
    const int wave = t >> 6, lane = t & 63;
    const int l16 = lane & 15, kg = lane >> 4;

    const int n = blockIdx.x & 7;
    const int o = (blockIdx.x >> 3) % 96;
    const int b = blockIdx.x / (8 * 96);
    const size_t base = ((size_t)b * 9216 + (size_t)o * ofac) * C_ + n * D_;

    if (t < 96) {
        const u16* gq = qb + base + (size_t)t * pstride;
        const u16* gk = kb + base + (size_t)t * pstride;
#pragma unroll
        for (int c = 0; c < 4; ++c) {
            *(int4*)&sQ[t][c * 8] = *(const int4*)(gq + c * 8);
            *(int4*)&sK[t][c * 8] = *(const int4*)(gk + c * 8);
        }
    }
#pragma unroll
    for (int p = 0; p < 3; ++p) {
        int j = p * 32 + (t >> 2);
        int dc = (t & 3) * 8;
        int4 raw = *(const int4*)(vin + base + (size_t)j * pstride + dc);
        const u16* e = (const u16*)&raw;
#pragma unroll
        for (int q = 0; q < 8; ++q) sVT[dc + q][j] = e[q];
    }
    __syncthreads();

    bf16x8 kf[6];
#pragma unroll
    for (int f = 0; f < 6; ++f)
        kf[f] = *(const bf16x8*)&sK[f * 16 + l16][kg * 8];

    const f32x4 zero = {0.f, 0.f, 0.f, 0.f};

    for (int p = 0; p < 3; ++p) {
        const int g = wave * 3 + p;
        bf16x8 qf = *(const bf16x8*)&sQ[g * 16 + l16][kg * 8];
        f32x4 s[6];
#pragma unroll
        for (int f = 0; f < 6; ++f)
            s[f] = __builtin_amdgcn_mfma_f32_16x16x32_bf16(kf[f], qf, zero, 0, 0, 0);

        float m = s[0][0];
#pragma unroll
        for (int f = 0; f < 6; ++f)
#pragma unroll
            for (int r = 0; r < 4; ++r) m = fmaxf(m, s[f][r]);
        m = fmaxf(m, __shfl_xor(m, 16));
        m = fmaxf(m, __shfl_xor(m, 32));
        float l = 0.f;
#pragma unroll
        for (int f = 0; f < 6; ++f)
#pragma unroll
            for (int r = 0; r < 4; ++r) l += __expf(s[f][r] - m);
        l += __shfl_xor(l, 16);
        l += __shfl_xor(l, 32);
        float lse = m + __logf(l);

        u16 ah[6][4];
#pragma unroll
        for (int f = 0; f < 6; ++f)
#pragma unroll
            for (int r = 0; r < 4; ++r)
                ah[f][r] = f2h(s[f][r] - lse);

        f32x4 pacc[2] = { zero, zero };
#pragma unroll
        for (int c = 0; c < 3; ++c) {
#pragma unroll
            for (int fi = 0; fi < 2; ++fi)
#pragma unroll
                for (int r = 0; r < 4; ++r)
                    sAh[wave][l16][fi * 16 + kg * 4 + r] = ah[2 * c + fi][r];
            hf8 ahf = *(const hf8*)&sAh[wave][l16][kg * 8];
#pragma unroll
            for (int nf = 0; nf < 2; ++nf) {
                hf8 vt = *(const hf8*)&sVT[nf * 16 + l16][c * 32 + kg * 8];
                pacc[nf] = __builtin_amdgcn_mfma_f32_16x16x32_f16(ahf, vt, pacc[nf], 0, 0, 0);
            }
        }

#pragma unroll
        for (int nf = 0; nf < 2; ++nf)
#pragma unroll
            for (int r = 0; r < 4; ++r) {
                int qi = g * 16 + kg * 4 + r;
                size_t off = base + (size_t)qi * pstride + nf * 16 + l16;
                if (HM == 0) {
                    ((u16*)vout)[off] = f2h(pacc[nf][r]);
                } else {
                    float lv = b2f(lep[off]);
                    ((u16*)vout)[off] = f2b(pacc[nf][r] + lv);
                }
            }
    }
}

// ---------------------------------------------------------------------------
// out_gemm: out = o2sum @ Wo + bo (lepe pre-added in axial<1>).
// R4 structure, fp32 scalar epilogue, 32KB LDS, bounds(256,3).
// ---------------------------------------------------------------------------
__global__ __launch_bounds__(256, 3) void out_gemm(
    const u16* __restrict__ o2b, const u16* __restrict__ WoT,
    const float* __restrict__ bo, float* __restrict__ out)
{
    __shared__ u16 sA[128 * 64];
    __shared__ u16 sB[128 * 64];
    const int t = threadIdx.x;
    const int colbase = blockIdx.x * 128;
    const int m0 = blockIdx.y * 128;
    const int wave = t >> 6, lane = t & 63;
    const int wr = wave >> 1, wc = wave & 1;
    const int l16 = lane & 15, kg = lane >> 4;
    const int lrow = lane >> 3;
    const int sslot = (lane & 7) ^ lrow;

    const u16* gA = o2b + (size_t)m0 * C_;
    const u16* gB = WoT + (size_t)colbase * C_;

    f32x4 acc[4][4];
#pragma unroll
    for (int i = 0; i < 4; ++i)
#pragma unroll
        for (int j = 0; j < 4; ++j) acc[i][j] = (f32x4){0.f, 0.f, 0.f, 0.f};

    STAGE4(gA, sA, 0); STAGE4(gB, sB, 0);
    for (int k0 = 0; k0 < 256; k0 += 64) {
        __syncthreads();
#pragma unroll
        for (int ks = 0; ks < 2; ++ks) {
            bf16x8 af[4], bf[4];
#pragma unroll
            for (int mi = 0; mi < 4; ++mi)
                af[mi] = FRAG4(sA, wr * 64 + mi * 16 + l16, ks);
#pragma unroll
            for (int ni = 0; ni < 4; ++ni)
                bf[ni] = FRAG4(sB, wc * 64 + ni * 16 + l16, ks);
#pragma unroll
            for (int mi = 0; mi < 4; ++mi)
#pragma unroll
                for (int ni = 0; ni < 4; ++ni)
                    acc[mi][ni] = __builtin_amdgcn_mfma_f32_16x16x32_bf16(
                        af[mi], bf[ni], acc[mi][ni], 0, 0, 0);
        }
        __syncthreads();
        if (k0 < 192) { STAGE4(gA, sA, k0 + 64); STAGE4(gB, sB, k0 + 64); }
    }

#pragma unroll
    for (int mi = 0; mi < 4; ++mi)
#pragma unroll
        for (int ni = 0; ni < 4; ++ni) {
            int col = colbase + wc * 64 + ni * 16 + l16;
            float bv_ = bo[col];
#pragma unroll
            for (int r = 0; r < 4; ++r) {
                int row = m0 + wr * 64 + mi * 16 + kg * 4 + r;
                out[(size_t)row * 256 + col] = acc[mi][ni][r] + bv_;
            }
        }
}

extern "C" void kernel_launch(void* const* d_in, const int* in_sizes, int n_in,
                              void* d_out, int out_size, void* d_ws, size_t ws_size,
                              hipStream_t stream)
{
    const float* x   = (const float*)d_in[0];
    const float* enc = (const float*)d_in[1];
    const float* Wq  = (const float*)d_in[2];
    const float* bq  = (const float*)d_in[3];
    const float* Wk  = (const float*)d_in[4];
    const float* bk  = (const float*)d_in[5];
    const float* Wv  = (const float*)d_in[6];
    const float* bv  = (const float*)d_in[7];
    const float* cw  = (const float*)d_in[8];
    const float* cb  = (const float*)d_in[9];
    const float* Wo  = (const float*)d_in[10];
    const float* bo  = (const float*)d_in[11];

    u16* qbuf = (u16*)d_ws;            // SZ bf16 (later out2+lepe)
    u16* kbuf = qbuf + SZ;             // SZ bf16
    u16* vbuf = kbuf + SZ;             // SZ f16
    u16* WT   = vbuf + SZ;             // 4 * 65536 bf16
    u16* cwh  = WT + 4 * 65536;        // 6400 f16
    u16* xb   = cwh + 6400;            // SZ bf16
    u16* lep  = xb + SZ;               // SZ bf16
    u16* v1h  = (u16*)d_out;           // width-stage PV output, f16, in d_out

    prep_all<<<10265, 256, 0, stream>>>(x, xb, Wq, Wk, Wv, Wo, WT, cw, cwh);
    proj_fused<<<dim3(4, 576), 256, 0, stream>>>(xb, enc, WT, bq, bk, bv, qbuf, kbuf, vbuf);
    dwconv5x5<<<1152, 256, 0, stream>>>(vbuf, cwh, cb, lep);
    // width: o = image row, positions = w (stride C_)
    axial<0><<<B_ * 96 * NH_, 128, 0, stream>>>(qbuf, kbuf, vbuf, v1h, nullptr, 96, 256);
    // height: o = image col, positions = h (stride 96*C_); out2+lepe -> qbuf
    axial<1><<<B_ * 96 * NH_, 128, 0, stream>>>(qbuf, kbuf, v1h, qbuf, lep, 1, 96 * 256);
    out_gemm<<<dim3(2, 576), 256, 0, stream>>>(qbuf, WT + 3 * 65536, bo, (float*)d_out);
}

// Round 14
// 262.751 us; speedup vs baseline: 1.0749x; 1.0749x over previous
//
#include <hip/hip_runtime.h>

#define B_ 8
#define S_ 96
#define C_ 256
#define NH_ 8
#define D_ 32
#define M_ (B_*S_*S_)
static const size_t SZ = (size_t)M_ * C_;

typedef unsigned short u16;
typedef short bf16x8 __attribute__((ext_vector_type(8)));
typedef _Float16 hf8 __attribute__((ext_vector_type(8)));
typedef float f32x4 __attribute__((ext_vector_type(4)));

__device__ __forceinline__ u16 f2b(float f) {                // fp32 -> bf16 RNE
    unsigned u = __float_as_uint(f);
    return (u16)((u + 0x7FFFu + ((u >> 16) & 1u)) >> 16);
}
__device__ __forceinline__ float b2f(u16 h) { return __uint_as_float(((unsigned)h) << 16); }
__device__ __forceinline__ u16 f2h(float f) {
    _Float16 h = (_Float16)f;
    return __builtin_bit_cast(u16, h);
}

__device__ __forceinline__ void gload16(const u16* g, u16* l) {
    __builtin_amdgcn_global_load_lds(
        (const __attribute__((address_space(1))) u16*)g,
        (__attribute__((address_space(3))) u16*)l, 16, 0, 0);
}

// ---------------------------------------------------------------------------
// prep_all: union of prep_x (blocks [0,9216)), prep_w ([9216,10240)),
// prep_cw ([10240,10265)). Homogeneous tiny paths: no LDS, low VGPR ->
// no resource coupling (unlike the failed proj_fused union).
// ---------------------------------------------------------------------------
__global__ __launch_bounds__(256) void prep_all(
    const float* __restrict__ x, u16* __restrict__ xb,
    const float* __restrict__ Wq, const float* __restrict__ Wk,
    const float* __restrict__ Wv, const float* __restrict__ Wo,
    u16* __restrict__ WT,
    const float* __restrict__ cw, u16* __restrict__ cwh)
{
    int bx = blockIdx.x;
    if (bx < 9216) {
        size_t base = ((size_t)bx * 256 + threadIdx.x) * 8;
        float4 a = *(const float4*)(x + base);
        float4 b = *(const float4*)(x + base + 4);
        u16 o[8] = { f2b(a.x), f2b(a.y), f2b(a.z), f2b(a.w),
                     f2b(b.x), f2b(b.y), f2b(b.z), f2b(b.w) };
        *(int4*)(xb + base) = *(int4*)o;
    } else if (bx < 10240) {
        int id = (bx - 9216) * 256 + threadIdx.x;
        int w = id >> 16;
        int r = id & 65535;
        int n = r >> 8;
        int kk = r & 255;
        const float* Wp = (w == 0) ? Wq : (w == 1) ? Wk : (w == 2) ? Wv : Wo;
        WT[(size_t)id] = f2b(Wp[(size_t)kk * 256 + n]);
    } else {
        int id = (bx - 10240) * 256 + threadIdx.x;
        cwh[id] = f2h(cw[id]);
    }
}

// ---------------------------------------------------------------------------
// R4-proven GEMM staging: BK=64, SINGLE buffer, global_load_lds w16,
// XOR-swizzled source slot (slot' = slot ^ (row&7)), linear LDS [128][64].
// ---------------------------------------------------------------------------
#define STAGE4(gbase, lds, k0)                                                  \
    _Pragma("unroll")                                                           \
    for (int i_ = 0; i_ < 4; ++i_) {                                            \
        int row8 = wave * 32 + i_ * 8;                                          \
        gload16((gbase) + (size_t)(row8 + lrow) * C_ + (k0) + sslot * 8,        \
                (lds) + row8 * 64);                                             \
    }
#define FRAG4(lds, rowi, ks) \
    (*(const bf16x8*)((lds) + (rowi) * 64 + (((ks) * 4 + kg) ^ ((rowi) & 7)) * 8))

// ---------------------------------------------------------------------------
// proj_q: q = bf16(xb @ Wq + bq). 32KB LDS, bounds(256,3).   [R12 verbatim]
// ---------------------------------------------------------------------------
__global__ __launch_bounds__(256, 3) void proj_q(
    const u16* __restrict__ xb, const u16* __restrict__ WT,
    const float* __restrict__ bq, u16* __restrict__ q)
{
    __shared__ u16 sA[128 * 64];
    __shared__ u16 sB[128 * 64];
    const int t = threadIdx.x;
    const int colbase = blockIdx.x * 128;
    const int m0 = blockIdx.y * 128;
    const int wave = t >> 6, lane = t & 63;
    const int wr = wave >> 1, wc = wave & 1;
    const int l16 = lane & 15, kg = lane >> 4;
    const int lrow = lane >> 3;
    const int sslot = (lane & 7) ^ lrow;

    const u16* gA = xb + (size_t)m0 * C_;
    const u16* gB = WT + (size_t)colbase * C_;

    f32x4 acc[4][4];
#pragma unroll
    for (int i = 0; i < 4; ++i)
#pragma unroll
        for (int j = 0; j < 4; ++j) acc[i][j] = (f32x4){0.f, 0.f, 0.f, 0.f};

    STAGE4(gA, sA, 0); STAGE4(gB, sB, 0);
    for (int k0 = 0; k0 < 256; k0 += 64) {
        __syncthreads();
#pragma unroll
        for (int ks = 0; ks < 2; ++ks) {
            bf16x8 af[4], bf[4];
#pragma unroll
            for (int mi = 0; mi < 4; ++mi)
                af[mi] = FRAG4(sA, wr * 64 + mi * 16 + l16, ks);
#pragma unroll
            for (int ni = 0; ni < 4; ++ni)
                bf[ni] = FRAG4(sB, wc * 64 + ni * 16 + l16, ks);
#pragma unroll
            for (int mi = 0; mi < 4; ++mi)
#pragma unroll
                for (int ni = 0; ni < 4; ++ni)
                    acc[mi][ni] = __builtin_amdgcn_mfma_f32_16x16x32_bf16(
                        af[mi], bf[ni], acc[mi][ni], 0, 0, 0);
        }
        __syncthreads();
        if (k0 < 192) { STAGE4(gA, sA, k0 + 64); STAGE4(gB, sB, k0 + 64); }
    }

#pragma unroll
    for (int mi = 0; mi < 4; ++mi)
#pragma unroll
        for (int ni = 0; ni < 4; ++ni) {
            int col = colbase + wc * 64 + ni * 16 + l16;
            float bqv = bq[col];
#pragma unroll
            for (int r = 0; r < 4; ++r) {
                int row = m0 + wr * 64 + mi * 16 + kg * 4 + r;
                q[(size_t)row * 256 + col] = f2b(acc[mi][ni][r] + bqv);
            }
        }
}

// ---------------------------------------------------------------------------
// proj_kv: k = bf16((xb@Wk + bk + enc)*scale); v = f16(xb@Wv + bv + enc).
// Shared-A dual GEMM, 48KB LDS, bounds(256,2).               [R12 verbatim]
// ---------------------------------------------------------------------------
__global__ __launch_bounds__(256, 2) void proj_kv(
    const u16* __restrict__ xb, const float* __restrict__ enc,
    const u16* __restrict__ WT,
    const float* __restrict__ bk, const float* __restrict__ bv,
    u16* __restrict__ k, u16* __restrict__ v)
{
    __shared__ u16 sA[128 * 64];
    __shared__ u16 sB0[128 * 64];
    __shared__ u16 sB1[128 * 64];
    const int t = threadIdx.x;
    const int colbase = blockIdx.x * 128;
    const int m0 = blockIdx.y * 128;
    const int wave = t >> 6, lane = t & 63;
    const int wr = wave >> 1, wc = wave & 1;
    const int l16 = lane & 15, kg = lane >> 4;
    const int lrow = lane >> 3;
    const int sslot = (lane & 7) ^ lrow;

    const u16* gA = xb + (size_t)m0 * C_;
    const u16* gB0 = WT + 65536 + (size_t)colbase * C_;
    const u16* gB1 = WT + 2 * 65536 + (size_t)colbase * C_;

    f32x4 acck[4][4], accv[4][4];
#pragma unroll
    for (int i = 0; i < 4; ++i)
#pragma unroll
        for (int j = 0; j < 4; ++j) {
            acck[i][j] = (f32x4){0.f, 0.f, 0.f, 0.f};
            accv[i][j] = (f32x4){0.f, 0.f, 0.f, 0.f};
        }

    STAGE4(gA, sA, 0); STAGE4(gB0, sB0, 0); STAGE4(gB1, sB1, 0);
    for (int k0 = 0; k0 < 256; k0 += 64) {
        __syncthreads();
#pragma unroll
        for (int ks = 0; ks < 2; ++ks) {
            bf16x8 af[4], b0[4], b1[4];
#pragma unroll
            for (int mi = 0; mi < 4; ++mi)
                af[mi] = FRAG4(sA, wr * 64 + mi * 16 + l16, ks);
#pragma unroll
            for (int ni = 0; ni < 4; ++ni) {
                b0[ni] = FRAG4(sB0, wc * 64 + ni * 16 + l16, ks);
                b1[ni] = FRAG4(sB1, wc * 64 + ni * 16 + l16, ks);
            }
#pragma unroll
            for (int mi = 0; mi < 4; ++mi)
#pragma unroll
                for (int ni = 0; ni < 4; ++ni) {
                    acck[mi][ni] = __builtin_amdgcn_mfma_f32_16x16x32_bf16(
                        af[mi], b0[ni], acck[mi][ni], 0, 0, 0);
                    accv[mi][ni] = __builtin_amdgcn_mfma_f32_16x16x32_bf16(
                        af[mi], b1[ni], accv[mi][ni], 0, 0, 0);
                }
        }
        __syncthreads();
        if (k0 < 192) { STAGE4(gA, sA, k0 + 64); STAGE4(gB0, sB0, k0 + 64); STAGE4(gB1, sB1, k0 + 64); }
    }

    const float SCALE = 0.17677669529663687f;
#pragma unroll
    for (int mi = 0; mi < 4; ++mi)
#pragma unroll
        for (int ni = 0; ni < 4; ++ni) {
            int col = colbase + wc * 64 + ni * 16 + l16;
            float bkv = bk[col], bvv = bv[col];
#pragma unroll
            for (int r = 0; r < 4; ++r) {
                int row = m0 + wr * 64 + mi * 16 + kg * 4 + r;
                size_t off = (size_t)row * 256 + col;
                float e = enc[off];
                k[off] = f2b((acck[mi][ni][r] + bkv + e) * SCALE);
                v[off] = f2h(accv[mi][ni][r] + bvv + e);
            }
        }
}

// ---------------------------------------------------------------------------
// dwconv5x5: v (f16) -> lepe (bf16), packed f16 math, 8 output pixels/thread.
// ---------------------------------------------------------------------------
__global__ __launch_bounds__(256) void dwconv5x5(
    const u16* __restrict__ vh, const u16* __restrict__ cwh,
    const float* __restrict__ cb, u16* __restrict__ lepeb)
{
    size_t tid = (size_t)blockIdx.x * 256 + threadIdx.x;
    int c8 = (int)(tid & 31);
    size_t rest = tid >> 5;
    int wi = (int)(rest % 12);
    size_t tmp = rest / 12;
    int h = (int)(tmp % S_);
    int b = (int)(tmp / S_);
    int w0 = wi * 8;
    int c0 = c8 * 8;

    hf8 z;
#pragma unroll
    for (int q = 0; q < 8; ++q) z[q] = (_Float16)0.f;
    hf8 acc[8] = { z, z, z, z, z, z, z, z };

#pragma unroll
    for (int dy = -2; dy <= 2; ++dy) {
        int hy = h + dy;
        if (hy < 0 || hy >= S_) continue;
        const u16* rowp = vh + (((size_t)b * S_ + hy) * S_) * C_ + c0;
        hf8 vr[12];
#pragma unroll
        for (int i = 0; i < 12; ++i) {
            int c = w0 - 2 + i;
            vr[i] = (c >= 0 && c < S_) ? *(const hf8*)(rowp + (size_t)c * C_) : z;
        }
#pragma unroll
        for (int dx = 0; dx < 5; ++dx) {
            hf8 ww = *(const hf8*)(cwh + (size_t)((dy + 2) * 5 + dx) * C_ + c0);
#pragma unroll
            for (int r = 0; r < 8; ++r) acc[r] += vr[dx + r] * ww;
        }
    }

    float4 cb0 = *(const float4*)(cb + c0);
    float4 cb1 = *(const float4*)(cb + c0 + 4);
    float cbv[8] = { cb0.x, cb0.y, cb0.z, cb0.w, cb1.x, cb1.y, cb1.z, cb1.w };
    size_t pix0 = ((size_t)b * S_ + h) * S_ + w0;
#pragma unroll
    for (int r = 0; r < 8; ++r) {
        u16 o[8];
#pragma unroll
        for (int q = 0; q < 8; ++q) o[q] = f2b((float)acc[r][q] + cbv[q]);
        *(int4*)(lepeb + (pix0 + r) * C_ + c0) = *(int4*)o;
    }
}

// ---------------------------------------------------------------------------
// axial<HM>: MFMA axial attention with LOG-softmax (R12 f16 version).
//  HM=0 (width):  vin = v (f16), vout = v1 (f16, d_out)
//  HM=1 (height): vin = v1 (f16), vout = bf16(out2 + lepe) into qbuf in-place
// ---------------------------------------------------------------------------
template<int HM>
__global__ __launch_bounds__(128, 3) void axial(
    const u16* __restrict__ qb, const u16* __restrict__ kb,
    const u16* __restrict__ vin, void* __restrict__ vout,
    const u16* __restrict__ lep, int ofac, int pstride)
{
    __shared__ u16 sQ[96][56];
    __shared__ u16 sK[96][56];
    __shared__ u16 sVT[32][104];
    __shared__ u16 sAh[2][16][40];

    const int t = threadIdx.x;
    const int wave = t >> 6, lane = t & 63;
    const int l16 = lane & 15, kg = lane >> 4;

    const int n = blockIdx.x & 7;
    const int o = (blockIdx.x >> 3) % 96;
    const int b = blockIdx.x / (8 * 96);
    const size_t base = ((size_t)b * 9216 + (size_t)o * ofac) * C_ + n * D_;

    if (t < 96) {
        const u16* gq = qb + base + (size_t)t * pstride;
        const u16* gk = kb + base + (size_t)t * pstride;
#pragma unroll
        for (int c = 0; c < 4; ++c) {
            *(int4*)&sQ[t][c * 8] = *(const int4*)(gq + c * 8);
            *(int4*)&sK[t][c * 8] = *(const int4*)(gk + c * 8);
        }
    }
#pragma unroll
    for (int p = 0; p < 3; ++p) {
        int j = p * 32 + (t >> 2);
        int dc = (t & 3) * 8;
        int4 raw = *(const int4*)(vin + base + (size_t)j * pstride + dc);
        const u16* e = (const u16*)&raw;
#pragma unroll
        for (int q = 0; q < 8; ++q) sVT[dc + q][j] = e[q];
    }
    __syncthreads();

    bf16x8 kf[6];
#pragma unroll
    for (int f = 0; f < 6; ++f)
        kf[f] = *(const bf16x8*)&sK[f * 16 + l16][kg * 8];

    const f32x4 zero = {0.f, 0.f, 0.f, 0.f};

    for (int p = 0; p < 3; ++p) {
        const int g = wave * 3 + p;
        bf16x8 qf = *(const bf16x8*)&sQ[g * 16 + l16][kg * 8];
        f32x4 s[6];
#pragma unroll
        for (int f = 0; f < 6; ++f)
            s[f] = __builtin_amdgcn_mfma_f32_16x16x32_bf16(kf[f], qf, zero, 0, 0, 0);

        float m = s[0][0];
#pragma unroll
        for (int f = 0; f < 6; ++f)
#pragma unroll
            for (int r = 0; r < 4; ++r) m = fmaxf(m, s[f][r]);
        m = fmaxf(m, __shfl_xor(m, 16));
        m = fmaxf(m, __shfl_xor(m, 32));
        float l = 0.f;
#pragma unroll
        for (int f = 0; f < 6; ++f)
#pragma unroll
            for (int r = 0; r < 4; ++r) l += __expf(s[f][r] - m);
        l += __shfl_xor(l, 16);
        l += __shfl_xor(l, 32);
        float lse = m + __logf(l);

        u16 ah[6][4];
#pragma unroll
        for (int f = 0; f < 6; ++f)
#pragma unroll
            for (int r = 0; r < 4; ++r)
                ah[f][r] = f2h(s[f][r] - lse);

        f32x4 pacc[2] = { zero, zero };
#pragma unroll
        for (int c = 0; c < 3; ++c) {
#pragma unroll
            for (int fi = 0; fi < 2; ++fi)
#pragma unroll
                for (int r = 0; r < 4; ++r)
                    sAh[wave][l16][fi * 16 + kg * 4 + r] = ah[2 * c + fi][r];
            hf8 ahf = *(const hf8*)&sAh[wave][l16][kg * 8];
#pragma unroll
            for (int nf = 0; nf < 2; ++nf) {
                hf8 vt = *(const hf8*)&sVT[nf * 16 + l16][c * 32 + kg * 8];
                pacc[nf] = __builtin_amdgcn_mfma_f32_16x16x32_f16(ahf, vt, pacc[nf], 0, 0, 0);
            }
        }

#pragma unroll
        for (int nf = 0; nf < 2; ++nf)
#pragma unroll
            for (int r = 0; r < 4; ++r) {
                int qi = g * 16 + kg * 4 + r;
                size_t off = base + (size_t)qi * pstride + nf * 16 + l16;
                if (HM == 0) {
                    ((u16*)vout)[off] = f2h(pacc[nf][r]);
                } else {
                    float lv = b2f(lep[off]);
                    ((u16*)vout)[off] = f2b(pacc[nf][r] + lv);
                }
            }
    }
}

// ---------------------------------------------------------------------------
// out_gemm: out = o2sum @ Wo + bo (lepe pre-added in axial<1>).
// R4 structure, fp32 scalar epilogue, 32KB LDS, bounds(256,3). [R12 verbatim]
// ---------------------------------------------------------------------------
__global__ __launch_bounds__(256, 3) void out_gemm(
    const u16* __restrict__ o2b, const u16* __restrict__ WoT,
    const float* __restrict__ bo, float* __restrict__ out)
{
    __shared__ u16 sA[128 * 64];
    __shared__ u16 sB[128 * 64];
    const int t = threadIdx.x;
    const int colbase = blockIdx.x * 128;
    const int m0 = blockIdx.y * 128;
    const int wave = t >> 6, lane = t & 63;
    const int wr = wave >> 1, wc = wave & 1;
    const int l16 = lane & 15, kg = lane >> 4;
    const int lrow = lane >> 3;
    const int sslot = (lane & 7) ^ lrow;

    const u16* gA = o2b + (size_t)m0 * C_;
    const u16* gB = WoT + (size_t)colbase * C_;

    f32x4 acc[4][4];
#pragma unroll
    for (int i = 0; i < 4; ++i)
#pragma unroll
        for (int j = 0; j < 4; ++j) acc[i][j] = (f32x4){0.f, 0.f, 0.f, 0.f};

    STAGE4(gA, sA, 0); STAGE4(gB, sB, 0);
    for (int k0 = 0; k0 < 256; k0 += 64) {
        __syncthreads();
#pragma unroll
        for (int ks = 0; ks < 2; ++ks) {
            bf16x8 af[4], bf[4];
#pragma unroll
            for (int mi = 0; mi < 4; ++mi)
                af[mi] = FRAG4(sA, wr * 64 + mi * 16 + l16, ks);
#pragma unroll
            for (int ni = 0; ni < 4; ++ni)
                bf[ni] = FRAG4(sB, wc * 64 + ni * 16 + l16, ks);
#pragma unroll
            for (int mi = 0; mi < 4; ++mi)
#pragma unroll
                for (int ni = 0; ni < 4; ++ni)
                    acc[mi][ni] = __builtin_amdgcn_mfma_f32_16x16x32_bf16(
                        af[mi], bf[ni], acc[mi][ni], 0, 0, 0);
        }
        __syncthreads();
        if (k0 < 192) { STAGE4(gA, sA, k0 + 64); STAGE4(gB, sB, k0 + 64); }
    }

#pragma unroll
    for (int mi = 0; mi < 4; ++mi)
#pragma unroll
        for (int ni = 0; ni < 4; ++ni) {
            int col = colbase + wc * 64 + ni * 16 + l16;
            float bv_ = bo[col];
#pragma unroll
            for (int r = 0; r < 4; ++r) {
                int row = m0 + wr * 64 + mi * 16 + kg * 4 + r;
                out[(size_t)row * 256 + col] = acc[mi][ni][r] + bv_;
            }
        }
}

extern "C" void kernel_launch(void* const* d_in, const int* in_sizes, int n_in,
                              void* d_out, int out_size, void* d_ws, size_t ws_size,
                              hipStream_t stream)
{
    const float* x   = (const float*)d_in[0];
    const float* enc = (const float*)d_in[1];
    const float* Wq  = (const float*)d_in[2];
    const float* bq  = (const float*)d_in[3];
    const float* Wk  = (const float*)d_in[4];
    const float* bk  = (const float*)d_in[5];
    const float* Wv  = (const float*)d_in[6];
    const float* bv  = (const float*)d_in[7];
    const float* cw  = (const float*)d_in[8];
    const float* cb  = (const float*)d_in[9];
    const float* Wo  = (const float*)d_in[10];
    const float* bo  = (const float*)d_in[11];

    u16* qbuf = (u16*)d_ws;            // SZ bf16 (later out2+lepe)
    u16* kbuf = qbuf + SZ;             // SZ bf16
    u16* vbuf = kbuf + SZ;             // SZ f16
    u16* WT   = vbuf + SZ;             // 4 * 65536 bf16
    u16* cwh  = WT + 4 * 65536;        // 6400 f16
    u16* xb   = cwh + 6400;            // SZ bf16
    u16* lep  = xb + SZ;               // SZ bf16
    u16* v1h  = (u16*)d_out;           // width-stage PV output, f16, in d_out

    prep_all<<<10265, 256, 0, stream>>>(x, xb, Wq, Wk, Wv, Wo, WT, cw, cwh);
    proj_q<<<dim3(2, 576), 256, 0, stream>>>(xb, WT, bq, qbuf);
    proj_kv<<<dim3(2, 576), 256, 0, stream>>>(xb, enc, WT, bk, bv, kbuf, vbuf);
    dwconv5x5<<<1152, 256, 0, stream>>>(vbuf, cwh, cb, lep);
    // width: o = image row, positions = w (stride C_)
    axial<0><<<B_ * 96 * NH_, 128, 0, stream>>>(qbuf, kbuf, vbuf, v1h, nullptr, 96, 256);
    // height: o = image col, positions = h (stride 96*C_); out2+lepe -> qbuf
    axial<1><<<B_ * 96 * NH_, 128, 0, stream>>>(qbuf, kbuf, v1h, qbuf, lep, 1, 96 * 256);
    out_gemm<<<dim3(2, 576), 256, 0, stream>>>(qbuf, WT + 3 * 65536, bo, (float*)d_out);
}